// Round 10
// baseline (183.385 us; speedup 1.0000x reference)
//
#include <hip/hip_runtime.h>
#include <cstdint>

// Problem constants (fixed by setup_inputs)
#define B_   4
#define N_   50000
#define K_   27
#define P_   (B_ * N_)           // 200000 points
#define L_   (P_ * K_)           // 5400000 flat entries (64 | L_)
#define S_   130                 // per-dim encoding stride
#define PL_  (S_ * S_)           // 16900 plane stride
#define KS_  (B_ * S_ * S_ * S_) // 8788000 linear table cells
#define W_   (L_ / 64)           // 84375 bitmap words
#define NBW  ((W_ + 255) / 256)  // 330 word-scan blocks
#define BIGP 0x7f7f7f7f          // empty marker (stencil adds <=26, stays < 2^31)

// ---- tiled table layout: 2(x) x 4(y) x 4(z) cells per 32-int (128B) tile ----
#define TX_  65                  // x tiles (130/2)
#define TY_  33                  // y tiles (ceil 130/4, padded to 132)
#define TZ_  33                  // z tiles (padded)
#define SLAB (TY_ * TZ_ * 32)    // ints per (b,bx) x-tile slab = 34848
#define MT_  (B_ * TX_ * SLAB)   // tiled table ints = 9058560 (div by 4)
#define XT4  (SLAB / 4)          // x-tile stride in int4 = 8712
#define ZITER ((PL_ + 511) / 512) // 34

__device__ __forceinline__ int tidx(int b, int cx, int cy, int cz) {
    int tile = ((b * TX_ + (cx >> 1)) * TY_ + (cy >> 2)) * TZ_ + (cz >> 2);
    return (tile << 5) + ((cx & 1) << 4) + ((cy & 3) << 2) + (cz & 3);
}

// linear point-table init (int4 BIGP fill)
__global__ __launch_bounds__(256) void k_init(int4* __restrict__ T4) {
    const int n4 = KS_ / 4;
    int4 v = make_int4(BIGP, BIGP, BIGP, BIGP);
    for (int i = blockIdx.x * blockDim.x + threadIdx.x; i < n4; i += gridDim.x * blockDim.x)
        T4[i] = v;
}

// linear table: Tlin[cell(p)] = min 32*p (200k atomics) + packed padded coords
__global__ __launch_bounds__(256) void k_ptab(const int* __restrict__ coords,
                                              const int* __restrict__ bidx,
                                              int* __restrict__ Tlin,
                                              int* __restrict__ bpt) {
    int p = blockIdx.x * blockDim.x + threadIdx.x;
    if (p >= P_) return;
    int b = bidx[p];
    int x = coords[3 * p + 0] + 1;   // 1..128
    int y = coords[3 * p + 1] + 1;
    int z = coords[3 * p + 2] + 1;
    bpt[p] = (b << 24) | (x << 16) | (y << 8) | z;
    atomicMin(&Tlin[((b * S_ + x) * S_ + y) * S_ + z], p << 5);
}

// Fused z+y min-plus stencil. One block per (b, x-tile): loads BOTH x-parities
// (33800 contiguous ints) into LDS, z-pass via register staging (single LDS
// buffer per plane), y-pass iterates TILED order -> coalesced tiled writes.
//   z: center +1 ; from z-1 +2 ; from z+1 +0
//   y: center +3 ; from y-1 +6 ; from y+1 +0
__global__ __launch_bounds__(512) void k_zy(const int* __restrict__ src,
                                            int* __restrict__ dstT) {
    __shared__ int pl0[PL_];   // 67.6 KB
    __shared__ int pl1[PL_];   // 67.6 KB (135.2 KB total)
    int blk = blockIdx.x;              // b*TX_ + bx
    const int* in = src + (size_t)blk * (2 * PL_);   // planes x=2bx, 2bx+1 contiguous
    int* outSlab   = dstT + (size_t)blk * SLAB;

    for (int i = threadIdx.x; i < 2 * PL_; i += 512) {
        int v = in[i];
        if (i < PL_) pl0[i] = v; else pl1[i - PL_] = v;
    }
    __syncthreads();

    #pragma unroll 2
    for (int q = 0; q < 2; ++q) {
        int* pq = q ? pl1 : pl0;
        int r[ZITER];
        // z-pass into registers (static indexing)
        #pragma unroll
        for (int it = 0; it < ZITER; ++it) {
            int j = threadIdx.x + it * 512;
            if (j < PL_) {
                int z = j % S_;
                int v = pq[j] + 1;
                if (z > 0)      v = min(v, pq[j - 1] + 2);
                if (z < S_ - 1) v = min(v, pq[j + 1]);
                r[it] = v;
            }
        }
        __syncthreads();
        #pragma unroll
        for (int it = 0; it < ZITER; ++it) {
            int j = threadIdx.x + it * 512;
            if (j < PL_) pq[j] = r[it];
        }
        __syncthreads();
        // y-pass in tiled output order: i indexes the 16-int parity-half of each tile
        for (int i = threadIdx.x; i < TY_ * TZ_ * 16; i += 512) {
            int t   = i >> 4;          // by*TZ_ + bz
            int off = i & 15;          // (y&3)*4 + (z&3)
            int by = t / TZ_, bz = t - by * TZ_;
            int y = by * 4 + (off >> 2), z = bz * 4 + (off & 3);
            if (y < S_ && z < S_) {
                int j = y * S_ + z;
                int v = pq[j] + 3;
                if (y > 0)      v = min(v, pq[j - S_] + 6);
                if (y < S_ - 1) v = min(v, pq[j + S_]);
                outSlab[(t << 5) + (q << 4) + off] = v;
            }
        }
        __syncthreads();
    }
}

// x min-plus stencil ON TILED layout: cx-1 / cx+1 are +-4 int4 within the tile
// or +-(XT4 -+ 4) across x-tiles. Three quasi-sequential streams, L2-absorbed.
//   center +9 ; from cx-1 +18 ; from cx+1 +0
__global__ __launch_bounds__(256) void k_x(const int4* __restrict__ src,
                                           int4* __restrict__ dst) {
    const int n4 = MT_ / 4;
    int i4 = blockIdx.x * blockDim.x + threadIdx.x;
    if (i4 >= n4) return;
    int w = i4 & 7;                    // int4 within tile
    int q = w >> 2;                    // x parity
    int tile = i4 >> 3;
    int rest = tile / TZ_;             // drop bz
    rest = rest / TY_;                 // drop by -> b*TX_ + bx
    int bx = rest % TX_;

    int4 c = src[i4];
    int4 v = make_int4(c.x + 9, c.y + 9, c.z + 9, c.w + 9);
    // from cx-1 (+18)
    if (q == 1) {
        int4 m = src[i4 - 4];
        v.x = min(v.x, m.x + 18); v.y = min(v.y, m.y + 18);
        v.z = min(v.z, m.z + 18); v.w = min(v.w, m.w + 18);
    } else if (bx > 0) {
        int4 m = src[i4 - XT4 + 4];
        v.x = min(v.x, m.x + 18); v.y = min(v.y, m.y + 18);
        v.z = min(v.z, m.z + 18); v.w = min(v.w, m.w + 18);
    }
    // from cx+1 (+0)
    if (q == 0) {
        int4 pp = src[i4 + 4];
        v.x = min(v.x, pp.x); v.y = min(v.y, pp.y);
        v.z = min(v.z, pp.z); v.w = min(v.w, pp.w);
    } else if (bx < TX_ - 1) {
        int4 pp = src[i4 + XT4 - 4];
        v.x = min(v.x, pp.x); v.y = min(v.y, pp.y);
        v.z = min(v.z, pp.z); v.w = min(v.w, pp.w);
    }
    dst[i4] = v;
}

// THE random pass: unpack bpt, tiled index (~4.5 lines/point), gather m32,
// ballot -> bitmap; out0/out2 fills ride under the fetch-bound gather.
__global__ __launch_bounds__(256) void k_gather(const int* __restrict__ bpt,
                                                const int* __restrict__ M,
                                                int* __restrict__ mArr,
                                                unsigned long long* __restrict__ bitmap,
                                                int* __restrict__ out0,
                                                int* __restrict__ out2) {
    int l = blockIdx.x * blockDim.x + threadIdx.x;
    if (l >= L_) return;
    int p = l / K_;
    int k = l - p * K_;
    out0[l] = p - (p / N_) * N_;   // n
    out2[l] = k;
    unsigned u = (unsigned)bpt[p];
    int b = u >> 24, x = (u >> 16) & 255, y = (u >> 8) & 255, z = u & 255;
    int dx = k / 9, dy = (k / 3) % 3, dz = k - (k / 3) * 3;
    int cx = x + dx - 1, cy = y + dy - 1, cz = z + dz - 1;   // 0..129
    int m32 = M[tidx(b, cx, cy, cz)];
    mArr[l] = m32;
    unsigned long long bal = __ballot(m32 == ((p << 5) | k));
    if ((threadIdx.x & 63) == 0) bitmap[l >> 6] = bal;
}

// per-word popcount + per-block exclusive scan over 84375 words
__global__ __launch_bounds__(256) void k_scan_words(const unsigned long long* __restrict__ bitmap,
                                                    int* __restrict__ wpre,
                                                    int* __restrict__ bsum) {
    __shared__ int sh[256];
    int w = blockIdx.x * 256 + threadIdx.x;
    int c = (w < W_) ? __popcll(bitmap[w]) : 0;
    sh[threadIdx.x] = c;
    __syncthreads();
    for (int off = 1; off < 256; off <<= 1) {
        int t = (threadIdx.x >= off) ? sh[threadIdx.x - off] : 0;
        __syncthreads();
        sh[threadIdx.x] += t;
        __syncthreads();
    }
    if (w < W_) wpre[w] = sh[threadIdx.x] - c;        // exclusive within block
    if (threadIdx.x == 255) bsum[blockIdx.x] = sh[255];
}

// single-block exclusive scan over the 330 block sums; emits num_unique
__global__ __launch_bounds__(512) void k_scan_block(int* __restrict__ bsum,
                                                    int* __restrict__ num_unique_out) {
    __shared__ int sh[512];
    int i = threadIdx.x;
    int v = (i < NBW) ? bsum[i] : 0;
    sh[i] = v;
    __syncthreads();
    for (int off = 1; off < 512; off <<= 1) {
        int t = (i >= off) ? sh[i - off] : 0;
        __syncthreads();
        sh[i] += t;
        __syncthreads();
    }
    if (i < NBW) bsum[i] = sh[i] - v;                 // global exclusive prefix
    if (i == 0) num_unique_out[0] = sh[511];
}

// rank via bitmap popcount (bitmap+wpre ~1.3MB, L2-resident); valid outkey
// rows written once; tail rows (>= num_unique) written -1 here (disjoint).
__global__ __launch_bounds__(256) void k_finalize(const int* __restrict__ coords,
                                                  const int* __restrict__ koffs,
                                                  const unsigned long long* __restrict__ bitmap,
                                                  const int* __restrict__ wpre,
                                                  const int* __restrict__ bsum,
                                                  const int* __restrict__ numuniq,
                                                  int* __restrict__ out1,   // holds m32, becomes output_idx
                                                  int* __restrict__ outkey) {
    int l = blockIdx.x * blockDim.x + threadIdx.x;
    if (l >= L_) return;
    int m32 = out1[l];
    int m = (m32 >> 5) * K_ + (m32 & 31);
    int w = m >> 6;
    unsigned long long word = bitmap[w];
    unsigned long long mask = (1ull << (m & 63)) - 1ull;
    int rank = wpre[w] + bsum[w >> 8] + (int)__popcll(word & mask);
    out1[l] = rank;
    if (m == l) {
        int p = l / K_;
        int k = l - p * K_;
        outkey[3 * rank + 0] = coords[3 * p + 0] + koffs[3 * k + 0];
        outkey[3 * rank + 1] = coords[3 * p + 1] + koffs[3 * k + 1];
        outkey[3 * rank + 2] = coords[3 * p + 2] + koffs[3 * k + 2];
    }
    if (l >= numuniq[0]) {
        outkey[3 * l + 0] = -1;
        outkey[3 * l + 1] = -1;
        outkey[3 * l + 2] = -1;
    }
}

extern "C" void kernel_launch(void* const* d_in, const int* in_sizes, int n_in,
                              void* d_out, int out_size, void* d_ws, size_t ws_size,
                              hipStream_t stream) {
    const int* coords = (const int*)d_in[0];   // [B,N,3] int32
    const int* bidx   = (const int*)d_in[1];   // [B,N]   int32
    const int* koffs  = (const int*)d_in[2];   // [27,3]  int32

    int* out      = (int*)d_out;
    int* out0     = out;            // input_idx      [L]
    int* out1     = out + L_;       // output_idx     [L] (holds m32 first)
    int* out2     = out + 2 * L_;   // rel_pos_idx    [L]
    int* outkey   = out + 3 * L_;   // output_key     [L,3]
    int* numuniq  = out + 6 * L_;   // num_unique     [1]

    // ws (~38.5 MB): table region (max(KS_, MT_) = MT_ ints; Tlin first, then
    // overwritten by tiled M after Tlin is dead) | bitmap | wpre | bsum | bpt
    int* Treg = (int*)d_ws;                                          // MT_ ints
    unsigned long long* bitmap = (unsigned long long*)(Treg + MT_);  // W_ u64
    int* wpre = (int*)(bitmap + W_);                                 // W_ ints
    int* bsum = wpre + W_;                                           // NBW ints
    int* bpt  = bsum + NBW;                                          // P_ ints

    // tiled ping buffer A in the (not-yet-written) outkey region:
    // MT_ ints <= 3*L_ ints; fully consumed by k_x before k_finalize writes outkey.
    int* A = outkey;

    k_init       <<<2048, 256, 0, stream>>>((int4*)Treg);                    // Tlin = BIGP
    k_ptab       <<<(P_ + 255) / 256, 256, 0, stream>>>(coords, bidx, Treg, bpt);
    k_zy         <<<B_ * TX_, 512, 0, stream>>>(Treg, A);                    // Tlin -> A (tiled)
    k_x          <<<(MT_ / 4 + 255) / 256, 256, 0, stream>>>((const int4*)A, (int4*)Treg); // A -> M (tiled)
    k_gather     <<<(L_ + 255) / 256, 256, 0, stream>>>(bpt, Treg, out1, bitmap, out0, out2);
    k_scan_words <<<NBW, 256, 0, stream>>>(bitmap, wpre, bsum);
    k_scan_block <<<1, 512, 0, stream>>>(bsum, numuniq);
    k_finalize   <<<(L_ + 255) / 256, 256, 0, stream>>>(coords, koffs, bitmap, wpre, bsum,
                                                        numuniq, out1, outkey);
}

// Round 11
// 150.393 us; speedup vs baseline: 1.2194x; 1.2194x over previous
//
#include <hip/hip_runtime.h>
#include <cstdint>

// Problem constants (fixed by setup_inputs)
#define B_   4
#define N_   50000
#define K_   27
#define P_   (B_ * N_)           // 200000 points
#define L_   (P_ * K_)           // 5400000 flat entries (64 | L_)
#define S_   130                 // per-dim encoding stride
#define PL_  (S_ * S_)           // 16900 plane stride (linear)
#define KS_  (B_ * S_ * S_ * S_) // 8788000 linear table cells
#define W_   (L_ / 64)           // 84375 bitmap words
#define NBW  ((W_ + 255) / 256)  // 330 word-scan blocks
#define BIGP 0x7f7f7f7f          // empty marker (stencil adds <=26, stays < 2^31)

// ---- plane-tiled layout: per (b,cx) plane, 4(y) x 8(z) cells per 128B line ----
#define TYT  33                  // y tiles (132/4)
#define TZT  17                  // z tiles (136/8)
#define PLT_ (TYT * TZT * 32)    // ints per tiled plane = 17952
#define PLT4 (PLT_ / 4)          // int4 plane stride = 4488
#define MT2_ (B_ * S_ * PLT_)    // tiled table ints = 9335040 (even)
#define TZP  132                 // LDS tz row stride (2-way max conflicts)

// linear point-table init (int4 BIGP fill)
__global__ __launch_bounds__(256) void k_init(int4* __restrict__ T4) {
    const int n4 = KS_ / 4;
    int4 v = make_int4(BIGP, BIGP, BIGP, BIGP);
    for (int i = blockIdx.x * blockDim.x + threadIdx.x; i < n4; i += gridDim.x * blockDim.x)
        T4[i] = v;
}

// linear table: Tlin[cell(p)] = min 32*p (200k atomics) + packed padded coords
__global__ __launch_bounds__(256) void k_ptab(const int* __restrict__ coords,
                                              const int* __restrict__ bidx,
                                              int* __restrict__ Tlin,
                                              int* __restrict__ bpt) {
    int p = blockIdx.x * blockDim.x + threadIdx.x;
    if (p >= P_) return;
    int b = bidx[p];
    int x = coords[3 * p + 0] + 1;   // 1..128
    int y = coords[3 * p + 1] + 1;
    int z = coords[3 * p + 2] + 1;
    bpt[p] = (b << 24) | (x << 16) | (y << 8) | z;
    atomicMin(&Tlin[((b * S_ + x) * S_ + y) * S_ + z], p << 5);
}

// Fused z+y min-plus stencil, one block per (b,cx) plane (R9-proven structure);
// only the OUTPUT order is tiled (4x8 lines), writes stay stride-1 coalesced.
//   z: center +1 ; from z-1 +2 ; from z+1 +0
//   y: center +3 ; from y-1 +6 ; from y+1 +0
__global__ __launch_bounds__(512) void k_zy(const int* __restrict__ src,
                                            int* __restrict__ dstT) {
    __shared__ int pl[PL_];        // 67.6 KB (row stride 130)
    __shared__ int tz[TZP * S_];   // 68.6 KB (row stride 132 -> <=2-way on tiled reads)
    const int* s = src + (size_t)blockIdx.x * PL_;
    int* d       = dstT + (size_t)blockIdx.x * PLT_;
    const int4* s4 = (const int4*)s;
    int4* pl4      = (int4*)pl;
    for (int i = threadIdx.x; i < PL_ / 4; i += 512) pl4[i] = s4[i];
    __syncthreads();
    for (int i = threadIdx.x; i < PL_; i += 512) {
        int y = i / S_, z = i - y * S_;
        int v = pl[i] + 1;
        if (z > 0)      v = min(v, pl[i - 1] + 2);
        if (z < S_ - 1) v = min(v, pl[i + 1]);
        tz[y * TZP + z] = v;
    }
    __syncthreads();
    for (int i = threadIdx.x; i < PLT_; i += 512) {
        int t = i >> 5, off = i & 31;
        int by = t / TZT, bz = t - by * TZT;
        int y = by * 4 + (off >> 3), z = bz * 8 + (off & 7);
        int v = BIGP;
        if (y < S_ && z < S_) {
            int j = y * TZP + z;
            v = tz[j] + 3;
            if (y > 0)      v = min(v, tz[j - TZP] + 6);
            if (y < S_ - 1) v = min(v, tz[j + TZP]);
        }
        d[i] = v;                  // stride-1 coalesced
    }
}

// x min-plus stencil on tiled planes (identical 3-stream form to R9's proven k_x,
// plane stride PLT4). Pads are inert: pad-in -> pad-out, never read by gather.
//   center +9 ; from cx-1 +18 ; from cx+1 +0
__global__ __launch_bounds__(256) void k_x(const int4* __restrict__ src,
                                           int4* __restrict__ dst) {
    const int n4 = MT2_ / 4;
    int i4 = blockIdx.x * blockDim.x + threadIdx.x;
    if (i4 >= n4) return;
    int x = (i4 / PLT4) % S_;
    int4 c = src[i4];
    int4 v = make_int4(c.x + 9, c.y + 9, c.z + 9, c.w + 9);
    if (x > 0) {
        int4 m = src[i4 - PLT4];
        v.x = min(v.x, m.x + 18); v.y = min(v.y, m.y + 18);
        v.z = min(v.z, m.z + 18); v.w = min(v.w, m.w + 18);
    }
    if (x < S_ - 1) {
        int4 pp = src[i4 + PLT4];
        v.x = min(v.x, pp.x); v.y = min(v.y, pp.y);
        v.z = min(v.z, pp.z); v.w = min(v.w, pp.w);
    }
    dst[i4] = v;
}

// THE random pass: unpack bpt, tiled index (~5.6 lines/point vs ~9.6 linear),
// gather m32, ballot -> bitmap; out0/out2 fills ride under the fetch-bound gather.
__global__ __launch_bounds__(256) void k_gather(const int* __restrict__ bpt,
                                                const int* __restrict__ M,
                                                int* __restrict__ mArr,
                                                unsigned long long* __restrict__ bitmap,
                                                int* __restrict__ out0,
                                                int* __restrict__ out2) {
    int l = blockIdx.x * blockDim.x + threadIdx.x;
    if (l >= L_) return;
    int p = l / K_;
    int k = l - p * K_;
    out0[l] = p - (p / N_) * N_;   // n
    out2[l] = k;
    unsigned u = (unsigned)bpt[p];
    int b = u >> 24, x = (u >> 16) & 255, y = (u >> 8) & 255, z = u & 255;
    int dx = k / 9, dy = (k / 3) % 3, dz = k - (k / 3) * 3;
    int cx = x + dx - 1, cy = y + dy - 1, cz = z + dz - 1;   // 0..129
    int idx = (b * S_ + cx) * PLT_
            + (((cy >> 2) * TZT + (cz >> 3)) << 5)
            + ((cy & 3) << 3) + (cz & 7);
    int m32 = M[idx];
    mArr[l] = m32;
    unsigned long long bal = __ballot(m32 == ((p << 5) | k));
    if ((threadIdx.x & 63) == 0) bitmap[l >> 6] = bal;
}

// per-word popcount + per-block exclusive scan over 84375 words
__global__ __launch_bounds__(256) void k_scan_words(const unsigned long long* __restrict__ bitmap,
                                                    int* __restrict__ wpre,
                                                    int* __restrict__ bsum) {
    __shared__ int sh[256];
    int w = blockIdx.x * 256 + threadIdx.x;
    int c = (w < W_) ? __popcll(bitmap[w]) : 0;
    sh[threadIdx.x] = c;
    __syncthreads();
    for (int off = 1; off < 256; off <<= 1) {
        int t = (threadIdx.x >= off) ? sh[threadIdx.x - off] : 0;
        __syncthreads();
        sh[threadIdx.x] += t;
        __syncthreads();
    }
    if (w < W_) wpre[w] = sh[threadIdx.x] - c;        // exclusive within block
    if (threadIdx.x == 255) bsum[blockIdx.x] = sh[255];
}

// single-block exclusive scan over the 330 block sums; emits num_unique
__global__ __launch_bounds__(512) void k_scan_block(int* __restrict__ bsum,
                                                    int* __restrict__ num_unique_out) {
    __shared__ int sh[512];
    int i = threadIdx.x;
    int v = (i < NBW) ? bsum[i] : 0;
    sh[i] = v;
    __syncthreads();
    for (int off = 1; off < 512; off <<= 1) {
        int t = (i >= off) ? sh[i - off] : 0;
        __syncthreads();
        sh[i] += t;
        __syncthreads();
    }
    if (i < NBW) bsum[i] = sh[i] - v;                 // global exclusive prefix
    if (i == 0) num_unique_out[0] = sh[511];
}

// rank via bitmap popcount (bitmap+wpre ~1.3MB, L2-resident); valid outkey
// rows written once; tail rows (>= num_unique) written -1 here (disjoint).
__global__ __launch_bounds__(256) void k_finalize(const int* __restrict__ coords,
                                                  const int* __restrict__ koffs,
                                                  const unsigned long long* __restrict__ bitmap,
                                                  const int* __restrict__ wpre,
                                                  const int* __restrict__ bsum,
                                                  const int* __restrict__ numuniq,
                                                  int* __restrict__ out1,   // holds m32, becomes output_idx
                                                  int* __restrict__ outkey) {
    int l = blockIdx.x * blockDim.x + threadIdx.x;
    if (l >= L_) return;
    int m32 = out1[l];
    int m = (m32 >> 5) * K_ + (m32 & 31);
    int w = m >> 6;
    unsigned long long word = bitmap[w];
    unsigned long long mask = (1ull << (m & 63)) - 1ull;
    int rank = wpre[w] + bsum[w >> 8] + (int)__popcll(word & mask);
    out1[l] = rank;
    if (m == l) {
        int p = l / K_;
        int k = l - p * K_;
        outkey[3 * rank + 0] = coords[3 * p + 0] + koffs[3 * k + 0];
        outkey[3 * rank + 1] = coords[3 * p + 1] + koffs[3 * k + 1];
        outkey[3 * rank + 2] = coords[3 * p + 2] + koffs[3 * k + 2];
    }
    if (l >= numuniq[0]) {
        outkey[3 * l + 0] = -1;
        outkey[3 * l + 1] = -1;
        outkey[3 * l + 2] = -1;
    }
}

extern "C" void kernel_launch(void* const* d_in, const int* in_sizes, int n_in,
                              void* d_out, int out_size, void* d_ws, size_t ws_size,
                              hipStream_t stream) {
    const int* coords = (const int*)d_in[0];   // [B,N,3] int32
    const int* bidx   = (const int*)d_in[1];   // [B,N]   int32
    const int* koffs  = (const int*)d_in[2];   // [27,3]  int32

    int* out      = (int*)d_out;
    int* out0     = out;            // input_idx      [L]
    int* out1     = out + L_;       // output_idx     [L] (holds m32 first)
    int* out2     = out + 2 * L_;   // rel_pos_idx    [L]
    int* outkey   = out + 3 * L_;   // output_key     [L,3]
    int* numuniq  = out + 6 * L_;   // num_unique     [1]

    // ws (~39.2 MB): table region (MT2_ ints; holds Tlin first, then tiled M)
    // | bitmap | wpre | bsum | bpt.  (R2 proved ws_size >= ~57MB.)
    int* Treg = (int*)d_ws;                                          // MT2_ ints
    unsigned long long* bitmap = (unsigned long long*)(Treg + MT2_); // W_ u64
    int* wpre = (int*)(bitmap + W_);                                 // W_ ints
    int* bsum = wpre + W_;                                           // NBW ints
    int* bpt  = bsum + NBW;                                          // P_ ints

    // tiled ping buffer A in the (not-yet-written) outkey region:
    // MT2_ = 9.34M ints <= 3*L_ = 16.2M ints; consumed by k_x before finalize.
    int* A = outkey;

    k_init       <<<2048, 256, 0, stream>>>((int4*)Treg);                    // Tlin = BIGP
    k_ptab       <<<(P_ + 255) / 256, 256, 0, stream>>>(coords, bidx, Treg, bpt);
    k_zy         <<<B_ * S_, 512, 0, stream>>>(Treg, A);                     // Tlin -> A (tiled)
    k_x          <<<(MT2_ / 4 + 255) / 256, 256, 0, stream>>>((const int4*)A, (int4*)Treg);
    k_gather     <<<(L_ + 255) / 256, 256, 0, stream>>>(bpt, Treg, out1, bitmap, out0, out2);
    k_scan_words <<<NBW, 256, 0, stream>>>(bitmap, wpre, bsum);
    k_scan_block <<<1, 512, 0, stream>>>(bsum, numuniq);
    k_finalize   <<<(L_ + 255) / 256, 256, 0, stream>>>(coords, koffs, bitmap, wpre, bsum,
                                                        numuniq, out1, outkey);
}

// Round 13
// 149.477 us; speedup vs baseline: 1.2268x; 1.0061x over previous
//
#include <hip/hip_runtime.h>
#include <cstdint>

// Problem constants (fixed by setup_inputs)
#define B_   4
#define N_   50000
#define K_   27
#define P_   (B_ * N_)           // 200000 points
#define L_   (P_ * K_)           // 5400000 flat entries
#define S_   130                 // per-dim encoding stride
#define PL_  (S_ * S_)           // 16900 plane stride
#define KS_  (B_ * S_ * S_ * S_) // 8788000 linear table cells (div by 4)
#define BIGP 0x7f7f7f7f          // empty marker (stencil adds <=26, stays < 2^31)
#define NB2  ((P_ + 1023) / 1024) // 196 point-scan blocks

// linear point-table init (int4 BIGP fill)
__global__ __launch_bounds__(256) void k_init(int4* __restrict__ T4) {
    const int n4 = KS_ / 4;
    int4 v = make_int4(BIGP, BIGP, BIGP, BIGP);
    for (int i = blockIdx.x * blockDim.x + threadIdx.x; i < n4; i += gridDim.x * blockDim.x)
        T4[i] = v;
}

// point table: Tlin[cell(p)] = min 32*p (200k atomics) + packed padded coords
__global__ __launch_bounds__(256) void k_ptab(const int* __restrict__ coords,
                                              const int* __restrict__ bidx,
                                              int* __restrict__ Tlin,
                                              int* __restrict__ bpt) {
    int p = blockIdx.x * blockDim.x + threadIdx.x;
    if (p >= P_) return;
    int b = bidx[p];
    int x = coords[3 * p + 0] + 1;   // 1..128
    int y = coords[3 * p + 1] + 1;
    int z = coords[3 * p + 2] + 1;
    bpt[p] = (b << 24) | (x << 16) | (y << 8) | z;
    atomicMin(&Tlin[((b * S_ + x) * S_ + y) * S_ + z], p << 5);
}

// Fused z+y min-plus stencil, one block per (b,cx) plane (R9-proven).
//   z: center +1 ; from z-1 +2 ; from z+1 +0
//   y: center +3 ; from y-1 +6 ; from y+1 +0
__global__ __launch_bounds__(512) void k_zy(const int* __restrict__ src,
                                            int* __restrict__ dst) {
    __shared__ int pl[PL_];   // 67.6 KB
    __shared__ int tz[PL_];   // 67.6 KB
    const int4* s4 = (const int4*)(src + (size_t)blockIdx.x * PL_);
    int4* d4       = (int4*)(dst + (size_t)blockIdx.x * PL_);
    int4* pl4      = (int4*)pl;
    for (int i = threadIdx.x; i < PL_ / 4; i += 512) pl4[i] = s4[i];
    __syncthreads();
    for (int i = threadIdx.x; i < PL_; i += 512) {
        int z = i % S_;
        int v = pl[i] + 1;
        if (z > 0)      v = min(v, pl[i - 1] + 2);
        if (z < S_ - 1) v = min(v, pl[i + 1]);
        tz[i] = v;
    }
    __syncthreads();
    for (int i = threadIdx.x; i < PL_ / 4; i += 512) {
        int4 o;
        int base = 4 * i;
        #pragma unroll
        for (int j = 0; j < 4; ++j) {
            int idx = base + j;
            int y = idx / S_;
            int v = tz[idx] + 3;
            if (y > 0)      v = min(v, tz[idx - S_] + 6);
            if (y < S_ - 1) v = min(v, tz[idx + S_]);
            ((int*)&o)[j] = v;
        }
        d4[i] = o;
    }
}

// x min-plus stencil, int4-vectorized (R9-proven).
//   center +9 ; from cx-1 +18 ; from cx+1 +0
__global__ __launch_bounds__(256) void k_x(const int4* __restrict__ src,
                                           int4* __restrict__ dst) {
    const int n4 = KS_ / 4;
    int i = blockIdx.x * blockDim.x + threadIdx.x;
    if (i >= n4) return;
    int x = (i / (PL_ / 4)) % S_;
    int4 c = src[i];
    int4 v = make_int4(c.x + 9, c.y + 9, c.z + 9, c.w + 9);
    if (x > 0) {
        int4 m = src[i - PL_ / 4];
        v.x = min(v.x, m.x + 18); v.y = min(v.y, m.y + 18);
        v.z = min(v.z, m.z + 18); v.w = min(v.w, m.w + 18);
    }
    if (x < S_ - 1) {
        int4 pp = src[i + PL_ / 4];
        v.x = min(v.x, pp.x); v.y = min(v.y, pp.y);
        v.z = min(v.z, pp.z); v.w = min(v.w, pp.w);
    }
    dst[i] = v;
}

// THE random pass: per point, 27 gathers (compile-time offsets, 27-deep MLP).
// Stores the 27 m32 values into the out1 region (m27) and the 27-bit
// first-occurrence mask (bit k = M[cell(p,k)] == (p<<5)|k).
__global__ __launch_bounds__(256) void k_mask(const int* __restrict__ bpt,
                                              const int* __restrict__ M,
                                              int* __restrict__ m27,
                                              unsigned* __restrict__ mask) {
    int p = blockIdx.x * blockDim.x + threadIdx.x;
    if (p >= P_) return;
    unsigned u = (unsigned)bpt[p];
    int b = u >> 24, x = (u >> 16) & 255, y = (u >> 8) & 255, z = u & 255;
    int base = ((b * S_ + x) * S_ + y) * S_ + z;
    int t0 = p << 5;
    unsigned msk = 0;
    int* o = m27 + p * K_;
    #pragma unroll
    for (int k = 0; k < K_; ++k) {
        const int dx = k / 9, dy = (k / 3) % 3, dz = k - (k / 3) * 3;
        const int off = (dx - 1) * PL_ + (dy - 1) * S_ + (dz - 1);  // compile-time
        int m32 = M[base + off];
        o[k] = m32;
        if (m32 == (t0 | k)) msk |= (1u << k);
    }
    mask[p] = msk;
}

// scan over per-point popcounts: per-block (1024 items) exclusive scan
__global__ __launch_bounds__(256) void k_scan1(const unsigned* __restrict__ mask,
                                               int* __restrict__ Cl,
                                               int* __restrict__ bsum) {
    __shared__ int sh[256];
    int base = blockIdx.x * 1024 + threadIdx.x * 4;
    int c[4], s = 0;
    #pragma unroll
    for (int j = 0; j < 4; ++j) {
        int p = base + j;
        int v = (p < P_) ? __popc(mask[p]) : 0;
        c[j] = v; s += v;
    }
    sh[threadIdx.x] = s;
    __syncthreads();
    for (int off = 1; off < 256; off <<= 1) {
        int t = (threadIdx.x >= off) ? sh[threadIdx.x - off] : 0;
        __syncthreads();
        sh[threadIdx.x] += t;
        __syncthreads();
    }
    int run = sh[threadIdx.x] - s;   // exclusive for this thread
    #pragma unroll
    for (int j = 0; j < 4; ++j) {
        int p = base + j;
        if (p < P_) Cl[p] = run;
        run += c[j];
    }
    if (threadIdx.x == 255) bsum[blockIdx.x] = sh[255];
}

// single-block exclusive scan over the 196 block sums; emits num_unique
__global__ __launch_bounds__(256) void k_scan2(int* __restrict__ bsum,
                                               int* __restrict__ num_unique_out) {
    __shared__ int sh[256];
    int i = threadIdx.x;
    int v = (i < NB2) ? bsum[i] : 0;
    sh[i] = v;
    __syncthreads();
    for (int off = 1; off < 256; off <<= 1) {
        int t = (i >= off) ? sh[i - off] : 0;
        __syncthreads();
        sh[i] += t;
        __syncthreads();
    }
    if (i < NB2) bsum[i] = sh[i] - v;                 // global exclusive prefix
    if (i == 0) num_unique_out[0] = sh[255];
}

// Output pass: m32 = m27[l] (coalesced); first-occ (p',k') = decode(m32);
// rank = Cl[p'] + bsum[p'>>10] + popc(mask[p'] & ((1<<k')-1)).
// Random reads hit mask/Cl (1.6MB, L2-resident). Writes all outputs once;
// out1[l] is read-then-overwritten by the same thread.
__global__ __launch_bounds__(256) void k_final(const unsigned* __restrict__ bpt,
                                               const unsigned* __restrict__ mask,
                                               const int* __restrict__ Cl,
                                               const int* __restrict__ bsum,
                                               const int* __restrict__ numuniq,
                                               int* __restrict__ out0,
                                               int* __restrict__ out1,
                                               int* __restrict__ out2,
                                               int* __restrict__ outkey) {
    int l = blockIdx.x * blockDim.x + threadIdx.x;
    if (l >= L_) return;
    int p = l / K_;
    int k = l - p * K_;
    int m32 = out1[l];                        // m27
    int pf = m32 >> 5, kf = m32 & 31;         // first-occurrence (p',k')
    int rank = Cl[pf] + bsum[pf >> 10] + (int)__popc(mask[pf] & ((1u << kf) - 1u));
    out0[l] = p - (p / N_) * N_;   // n
    out1[l] = rank;
    out2[l] = k;
    if (m32 == ((p << 5) | k)) {   // l is itself the first occurrence: emit key
        unsigned u = bpt[p];
        int dx = k / 9, dy = (k / 3) % 3, dz = k - (k / 3) * 3;
        outkey[3 * rank + 0] = (int)((u >> 16) & 255) + dx - 2;  // (x+1)+(dx-1)-1
        outkey[3 * rank + 1] = (int)((u >> 8) & 255) + dy - 2;
        outkey[3 * rank + 2] = (int)(u & 255) + dz - 2;
    }
    if (l >= numuniq[0]) {         // tail row l -> -1 (disjoint from valid rows)
        outkey[3 * l + 0] = -1;
        outkey[3 * l + 1] = -1;
        outkey[3 * l + 2] = -1;
    }
}

extern "C" void kernel_launch(void* const* d_in, const int* in_sizes, int n_in,
                              void* d_out, int out_size, void* d_ws, size_t ws_size,
                              hipStream_t stream) {
    const int* coords = (const int*)d_in[0];   // [B,N,3] int32
    const int* bidx   = (const int*)d_in[1];   // [B,N]   int32
    const int* koffs  = (const int*)d_in[2];   // [27,3]  int32
    (void)koffs;

    int* out      = (int*)d_out;
    int* out0     = out;            // input_idx      [L]
    int* out1     = out + L_;       // output_idx     [L] (holds m27 first)
    int* out2     = out + 2 * L_;   // rel_pos_idx    [L]
    int* outkey   = out + 3 * L_;   // output_key     [L,3]
    int* numuniq  = out + 6 * L_;   // num_unique     [1]

    // ws (~37.6 MB): Tlin/M | bpt | mask | Cl | bsum
    int* Treg = (int*)d_ws;                       // KS_ ints (Tlin, then M)
    int* bpt  = Treg + KS_;                       // P_ ints
    unsigned* mask = (unsigned*)(bpt + P_);       // P_ u32
    int* Cl   = (int*)(mask + P_);                // P_ ints
    int* bsum = Cl + P_;                          // NB2 ints

    // stencil ping buffer A in the (not-yet-written) outkey region:
    // KS_ ints <= 3*L_ ints; fully consumed by k_x before k_final writes outkey.
    int* A = outkey;

    k_init  <<<2048, 256, 0, stream>>>((int4*)Treg);                    // Tlin = BIGP
    k_ptab  <<<(P_ + 255) / 256, 256, 0, stream>>>(coords, bidx, Treg, bpt);
    k_zy    <<<B_ * S_, 512, 0, stream>>>(Treg, A);                     // Tlin -> A
    k_x     <<<(KS_ / 4 + 255) / 256, 256, 0, stream>>>((const int4*)A, (int4*)Treg); // A -> M
    k_mask  <<<(P_ + 255) / 256, 256, 0, stream>>>(bpt, Treg, out1, mask);
    k_scan1 <<<NB2, 256, 0, stream>>>(mask, Cl, bsum);
    k_scan2 <<<1, 256, 0, stream>>>(bsum, numuniq);
    k_final <<<(L_ + 255) / 256, 256, 0, stream>>>((const unsigned*)bpt, mask, Cl, bsum,
                                                   numuniq, out0, out1, out2, outkey);
}